// Round 3
// baseline (428.220 us; speedup 1.0000x reference)
//
#include <hip/hip_runtime.h>
#include <hip/hip_bf16.h>

// ---------------------------------------------------------------------------
// MMD loss:  mmd = 2*Sxx_upper/(n(n-1)) + 2*Syy_upper/(m(m-1)) - 2*Sxy/(n*m)
// k(a,b) = exp(-|a-b|^2 / 128)  (sigma^2 = D = 64), N = M = 8192, D = 64.
//
// Algebra: store A' = A * sqrt(log2e)/8 in bf16 and s = 0.5*|a'|^2 (f32).
// Then  exp(-|a-b|^2/128) = exp2( dot(a',b') - s_a - s_b ).
// Epilogue per element: init acc = -(s_a+s_b), MFMA, min(acc,0),
// v_exp_f32 (exp2), accumulate.
//
// Lesson from R1: this kernel is latency-bound on L2 and hides latency via
// TLP. Keep VGPRs <= 64 (8 waves/SIMD) via __launch_bounds__(256, 8).
// No manual double-buffering; loads sit right before use and peer waves hide
// the latency. sy (col norms) are hoisted to the block prologue so they never
// sit on the MFMA dep chain.
// ---------------------------------------------------------------------------

using short8 = __attribute__((ext_vector_type(8))) short;  // 8 bf16 (4 VGPRs)
using f32x4  = __attribute__((ext_vector_type(4))) float;  // 4 fp32

#define NROWS 8192
#define DDIM  64
#define TOTAL_MAIN_BLOCKS (32 * 64 * 3)

// sqrt(log2(e)) / 8
#define PRESCALE 0.15014030109830622f

#if __has_builtin(__builtin_amdgcn_exp2f)
#define EXP2F(x) __builtin_amdgcn_exp2f(x)
#else
#define EXP2F(x) exp2f(x)
#endif

// ---------------------------------------------------------------------------
// Prep: normalize X, prescale, cast X/Y to bf16, compute s = 0.5*|row'|^2
// from the bf16-rounded values (consistent with the MFMA inputs).
// Also resets the fused-finalize accumulator + arrival counter.
// ---------------------------------------------------------------------------
__global__ __launch_bounds__(256) void mmd_prep(
    const float* __restrict__ z_seq, const float* __restrict__ pmean,
    const float* __restrict__ pstd, const float* __restrict__ z_prior,
    __hip_bfloat16* __restrict__ Xb, __hip_bfloat16* __restrict__ Yb,
    float* __restrict__ sxx, float* __restrict__ syy,
    double* __restrict__ acc, unsigned* __restrict__ cnt)
{
    const int tid  = threadIdx.x;
    if (blockIdx.x == 0 && tid == 0) { *acc = 0.0; *cnt = 0u; }

    const int lane = tid & 63;
    const int wid  = tid >> 6;
    const int row  = blockIdx.x * 4 + wid;   // 0..16383 (X rows then Y rows)

    float v;
    __hip_bfloat16* dst;
    float* sdst;
    int r;
    if (row < NROWS) {
        r = row;
        v = (z_seq[(size_t)r * DDIM + lane] - pmean[lane]) / pstd[lane];
        dst = Xb; sdst = sxx;
    } else {
        r = row - NROWS;
        v = z_prior[(size_t)r * DDIM + lane];
        dst = Yb; sdst = syy;
    }
    __hip_bfloat16 hb = __float2bfloat16(v * PRESCALE);
    dst[(size_t)r * DDIM + lane] = hb;

    float vb = __bfloat162float(hb);
    float sq = vb * vb;
#pragma unroll
    for (int off = 32; off; off >>= 1) sq += __shfl_xor(sq, off, 64);
    if (lane == 0) sdst[r] = 0.5f * sq;
}

// ---------------------------------------------------------------------------
// Per-thread tile compute for one 128(i) x 256(j) block; wave tile 64x128.
// SYM known at compile time. Loads stay adjacent to their use (TLP hides
// latency); only the small sy vector is hoisted.
// ---------------------------------------------------------------------------
template<bool SYM>
__device__ __forceinline__ float mmd_block(
    const __hip_bfloat16* __restrict__ A, const __hip_bfloat16* __restrict__ Bp,
    const float* __restrict__ sa, const float* __restrict__ sb,
    int iBlock, int jBlock)
{
    const int tid  = threadIdx.x;
    const int lane = tid & 63;
    const int wid  = tid >> 6;
    const int quad = lane >> 4;
    const int l15  = lane & 15;

    const int i0 = iBlock + (wid >> 1) * 64;   // wave row origin
    const int j0 = jBlock + (wid & 1) * 128;   // wave col origin

    // Persistent A fragments + negated row norms.
    short8 af[4][2];
    f32x4  nsx[4];
#pragma unroll
    for (int mt = 0; mt < 4; ++mt) {
        const int ar = i0 + mt * 16 + l15;
#pragma unroll
        for (int ks = 0; ks < 2; ++ks)
            af[mt][ks] = *reinterpret_cast<const short8*>(
                A + (size_t)ar * DDIM + ks * 32 + quad * 8);
        f32x4 s4 = *reinterpret_cast<const f32x4*>(sa + i0 + mt * 16 + quad * 4);
        nsx[mt] = -s4;
    }

    // Hoisted negated column norms for this lane's 8 j-tiles.
    float nsy[8];
#pragma unroll
    for (int nt = 0; nt < 8; ++nt) nsy[nt] = -sb[j0 + l15 + nt * 16];

    const __hip_bfloat16* bbase = Bp + (size_t)(j0 + l15) * DDIM + quad * 8;

    float lsum = 0.0f;

#pragma unroll
    for (int nt = 0; nt < 8; ++nt) {
        const int jt = j0 + nt * 16;
        if (SYM && jt < i0) continue;    // all 4 mt-tiles below diagonal

        const __hip_bfloat16* bp = bbase + (size_t)nt * 16 * DDIM;
        short8 b0 = *reinterpret_cast<const short8*>(bp);
        short8 b1 = *reinterpret_cast<const short8*>(bp + 32);

#pragma unroll
        for (int mt = 0; mt < 4; ++mt) {
            const int it = i0 + mt * 16;
            if (SYM && jt < it) continue;          // tile strictly below diag

            f32x4 acc;
#pragma unroll
            for (int r = 0; r < 4; ++r) acc[r] = nsx[mt][r] + nsy[nt];
            acc = __builtin_amdgcn_mfma_f32_16x16x32_bf16(af[mt][0], b0, acc, 0, 0, 0);
            acc = __builtin_amdgcn_mfma_f32_16x16x32_bf16(af[mt][1], b1, acc, 0, 0, 0);

            if (SYM && jt == it) {
                // diagonal tile: count only j > i (trace excluded exactly)
#pragma unroll
                for (int r = 0; r < 4; ++r) {
                    float v = EXP2F(fminf(acc[r], 0.0f));
                    lsum += (l15 > quad * 4 + r) ? v : 0.0f;
                }
            } else {
#pragma unroll
                for (int r = 0; r < 4; ++r)
                    lsum += EXP2F(fminf(acc[r], 0.0f));
            }
        }
    }
    return lsum;
}

// ---------------------------------------------------------------------------
// Main: grid (32 jblocks, 64 iblocks, 3 modes). Block tile 128(i) x 256(j),
// 4 waves in 2x2. mode 0: XX (sym), 1: YY (sym), 2: XY (full).
// __launch_bounds__(256, 8): cap VGPRs at 64 so 8 waves/SIMD fit (R1 lesson).
// Fused finalize via double atomicAdd + arrival counter.
// ---------------------------------------------------------------------------
__global__ __launch_bounds__(256, 8) void mmd_main(
    const __hip_bfloat16* __restrict__ Xb, const __hip_bfloat16* __restrict__ Yb,
    const float* __restrict__ sxx, const float* __restrict__ syy,
    double* __restrict__ acc, unsigned* __restrict__ cnt,
    float* __restrict__ out)
{
    const int mode = blockIdx.z;
    const int bj = blockIdx.x;          // 0..31  (256-wide j blocks)
    const int bi = blockIdx.y;          // 0..63  (128-tall i blocks)
    const int iBlock = bi * 128;
    const int jBlock = bj * 256;
    const int tid = threadIdx.x;

    float lsum = 0.0f;
    const bool active = !(mode < 2 && (jBlock + 256 <= iBlock));

    if (active) {
        if (mode == 0)      lsum = mmd_block<true >(Xb, Xb, sxx, sxx, iBlock, jBlock);
        else if (mode == 1) lsum = mmd_block<true >(Yb, Yb, syy, syy, iBlock, jBlock);
        else                lsum = mmd_block<false>(Xb, Yb, sxx, syy, iBlock, jBlock);
    }

    // wave reduce
#pragma unroll
    for (int off = 32; off; off >>= 1) lsum += __shfl_xor(lsum, off, 64);

    __shared__ float ws4[4];
    const int lane = tid & 63, wid = tid >> 6;
    if (lane == 0) ws4[wid] = lsum;
    __syncthreads();
    if (tid == 0) {
        double tot = (double)ws4[0] + (double)ws4[1] + (double)ws4[2] + (double)ws4[3];
        // sym coefficient folds the x2 for sum_{i!=j} = 2 * sum_{j>i}
        const double c = (mode < 2) ? (2.0 / (8192.0 * 8191.0))
                                    : (-2.0 / (8192.0 * 8192.0));
        if (tot != 0.0) atomicAdd(acc, tot * c);
        __threadfence();
        unsigned done = atomicAdd(cnt, 1u);
        if (done == TOTAL_MAIN_BLOCKS - 1) {
            __threadfence();
            double v = *(volatile double*)acc;   // all adds visible: we're last
            out[0] = (float)(v > 0.0 ? v : 0.0);
        }
    }
}

// ---------------------------------------------------------------------------
extern "C" void kernel_launch(void* const* d_in, const int* in_sizes, int n_in,
                              void* d_out, int out_size, void* d_ws, size_t ws_size,
                              hipStream_t stream) {
    const float* z_seq   = (const float*)d_in[0];   // [16,512,64]
    const float* pmean   = (const float*)d_in[1];   // [64]
    const float* pstd    = (const float*)d_in[2];   // [64]
    const float* z_prior = (const float*)d_in[3];   // [8192,64]
    float* out = (float*)d_out;

    char* ws = (char*)d_ws;
    __hip_bfloat16* Xb = (__hip_bfloat16*)(ws);                    // 1 MB
    __hip_bfloat16* Yb = (__hip_bfloat16*)(ws + (1u << 20));       // 1 MB
    float* sxx = (float*)(ws + (2u << 20));                        // 32 KB
    float* syy = (float*)(ws + (2u << 20) + 32768);                // 32 KB
    double* acc = (double*)(ws + (2u << 20) + 65536);              // 8 B
    unsigned* cnt = (unsigned*)(ws + (2u << 20) + 65536 + 64);     // 4 B

    mmd_prep<<<dim3(4096), dim3(256), 0, stream>>>(
        z_seq, pmean, pstd, z_prior, Xb, Yb, sxx, syy, acc, cnt);
    mmd_main<<<dim3(32, 64, 3), dim3(256), 0, stream>>>(
        Xb, Yb, sxx, syy, acc, cnt, out);
}

// Round 4
// 197.515 us; speedup vs baseline: 2.1680x; 2.1680x over previous
//
#include <hip/hip_runtime.h>
#include <hip/hip_bf16.h>

// ---------------------------------------------------------------------------
// MMD loss:  mmd = 2*Sxx_upper/(n(n-1)) + 2*Syy_upper/(m(m-1)) - 2*Sxy/(n*m)
// k(a,b) = exp(-|a-b|^2 / 128)  (sigma^2 = D = 64), N = M = 8192, D = 64.
//
// Algebra: store A' = A * sqrt(log2e)/8 in bf16 and s = 0.5*|a'|^2 (f32).
// Then  exp(-|a-b|^2/128) = exp2( dot(a',b') - s_a - s_b ).
// MFMA C-init = -s_a (REGISTER data, prologue-loaded -> no load on the MFMA
// input chain).  Post-MFMA per element: sub(s_b), v_exp_f32, accumulate.
// 12 VALU-class ops per 16x16 tile (was 24 in the 141us baseline).
//
// Hard-won structure lessons (R0..R3):
//  - default __launch_bounds__(256) ONLY. (256,8) -> compiler spills to
//    scratch (203MB writes, 373us). No cap -> 44-64 VGPR, best.
//  - runtime `sym` + in-loop guards keep the scheduler from ballooning
//    registers via cross-iteration hoisting (templated straight-line body
//    hit 108 VGPR / half occupancy / 2x time in R1).
//  - loads stay adjacent to use; TLP (peer waves) hides L2 latency.
// ---------------------------------------------------------------------------

using short8  = __attribute__((ext_vector_type(8))) short;  // 8 bf16 (4 VGPRs)
using f32x4   = __attribute__((ext_vector_type(4))) float;  // 4 fp32
using float4v = __attribute__((ext_vector_type(4))) float;

#define NROWS 8192
#define DDIM  64
#define TOTAL_MAIN_BLOCKS (32 * 64 * 3)

// sqrt(log2(e)) / 8
#define PRESCALE 0.15014030109830622f

__device__ __forceinline__ float exp2_fast(float x) {
#if __has_builtin(__builtin_amdgcn_exp2f)
    return __builtin_amdgcn_exp2f(x);
#else
    float r;
    asm volatile("v_exp_f32 %0, %1\n\ts_nop 1" : "=v"(r) : "v"(x));
    return r;
#endif
}

// ---------------------------------------------------------------------------
// Prep: normalize X, prescale, cast X/Y to bf16, compute s = 0.5*|row'|^2
// from the bf16-rounded values (consistent with the MFMA inputs).
// 4 rows per wave, float4 loads. Also resets fused-finalize acc + counter.
// ---------------------------------------------------------------------------
__global__ __launch_bounds__(256) void mmd_prep(
    const float* __restrict__ z_seq, const float* __restrict__ pmean,
    const float* __restrict__ pstd, const float* __restrict__ z_prior,
    __hip_bfloat16* __restrict__ Xb, __hip_bfloat16* __restrict__ Yb,
    float* __restrict__ sxx, float* __restrict__ syy,
    double* __restrict__ acc, unsigned* __restrict__ cnt)
{
    const int tid = threadIdx.x;
    if (blockIdx.x == 0 && tid == 0) { *acc = 0.0; *cnt = 0u; }

    const int lane = tid & 63;
    const int wid  = tid >> 6;
    const int w    = blockIdx.x * 4 + wid;       // wave id, 0..4095
    const int sub  = lane >> 4;                  // row within wave, 0..3
    const int row  = w * 4 + sub;                // 0..16383
    const int d0   = (lane & 15) * 4;            // dim offset, 0..60

    float4v v;
    __hip_bfloat16* dst;
    float* sdst;
    int r;
    if (row < NROWS) {
        r = row;
        float4v z = *reinterpret_cast<const float4v*>(z_seq + (size_t)r * DDIM + d0);
        float4v pm = *reinterpret_cast<const float4v*>(pmean + d0);
        float4v ps = *reinterpret_cast<const float4v*>(pstd + d0);
#pragma unroll
        for (int k = 0; k < 4; ++k) v[k] = (z[k] - pm[k]) / ps[k];
        dst = Xb; sdst = sxx;
    } else {
        r = row - NROWS;
        v = *reinterpret_cast<const float4v*>(z_prior + (size_t)r * DDIM + d0);
        dst = Yb; sdst = syy;
    }

    ushort4 hb;
    float sq = 0.0f;
#pragma unroll
    for (int k = 0; k < 4; ++k) {
        __hip_bfloat16 b = __float2bfloat16(v[k] * PRESCALE);
        reinterpret_cast<__hip_bfloat16*>(&hb)[k] = b;
        float vb = __bfloat162float(b);
        sq += vb * vb;
    }
    *reinterpret_cast<ushort4*>(dst + (size_t)r * DDIM + d0) = hb;

    // reduce across the 16 lanes of this row-group (xor<16 stays in group)
#pragma unroll
    for (int off = 8; off; off >>= 1) sq += __shfl_xor(sq, off, 64);
    if ((lane & 15) == 0) sdst[r] = 0.5f * sq;
}

// ---------------------------------------------------------------------------
// Main: grid (32 jblocks, 64 iblocks, 3 modes). Block tile 128(i) x 256(j),
// 4 waves in 2x2, wave tile 64x128.  mode 0: XX (sym), 1: YY (sym), 2: XY.
// Fused finalize via double atomicAdd + arrival counter.
// ---------------------------------------------------------------------------
__global__ __launch_bounds__(256) void mmd_main(
    const __hip_bfloat16* __restrict__ Xb, const __hip_bfloat16* __restrict__ Yb,
    const float* __restrict__ sxx, const float* __restrict__ syy,
    double* __restrict__ acc, unsigned* __restrict__ cnt,
    float* __restrict__ out)
{
    const int mode = blockIdx.z;
    const int bj = blockIdx.x;          // 0..31  (256-wide j blocks)
    const int bi = blockIdx.y;          // 0..63  (128-tall i blocks)

    const __hip_bfloat16* A;
    const __hip_bfloat16* Bp;
    const float* sa;
    const float* sb;
    if (mode == 0)      { A = Xb; Bp = Xb; sa = sxx; sb = sxx; }
    else if (mode == 1) { A = Yb; Bp = Yb; sa = syy; sb = syy; }
    else                { A = Xb; Bp = Yb; sa = sxx; sb = syy; }
    const bool sym = (mode < 2);

    const int tid  = threadIdx.x;
    const int lane = tid & 63;
    const int wid  = tid >> 6;
    const int quad = lane >> 4;
    const int l15  = lane & 15;

    const int iBlock = bi * 128;
    const int jBlock = bj * 256;
    const bool active = !(sym && (jBlock + 256 <= iBlock));

    float lsum = 0.0f;

    if (active) {
        const int i0 = iBlock + (wid >> 1) * 64;   // wave row origin
        const int j0 = jBlock + (wid & 1) * 128;   // wave col origin

        // Persistent A fragments + negated row half-norms (MFMA C-init).
        short8 af[4][2];
        f32x4  nsx[4];
#pragma unroll
        for (int mt = 0; mt < 4; ++mt) {
            const int ar = i0 + mt * 16 + l15;
#pragma unroll
            for (int ks = 0; ks < 2; ++ks)
                af[mt][ks] = *reinterpret_cast<const short8*>(
                    A + (size_t)ar * DDIM + ks * 32 + quad * 8);
            f32x4 s4 = *reinterpret_cast<const f32x4*>(sa + i0 + mt * 16 + quad * 4);
            nsx[mt] = -s4;
        }

        const __hip_bfloat16* bbase = Bp + (size_t)(j0 + l15) * DDIM + quad * 8;

#pragma unroll
        for (int nt = 0; nt < 8; ++nt) {
            const int jt = j0 + nt * 16;
            if (sym && jt < i0) continue;    // all 4 mt-tiles below diagonal

            const __hip_bfloat16* bp = bbase + (size_t)nt * 16 * DDIM;
            short8 b0 = *reinterpret_cast<const short8*>(bp);
            short8 b1 = *reinterpret_cast<const short8*>(bp + 32);
            const float syv = sb[jt + l15];  // col half-norm (post-MFMA use)

#pragma unroll
            for (int mt = 0; mt < 4; ++mt) {
                const int it = i0 + mt * 16;
                if (sym && jt < it) continue;          // tile below diagonal

                f32x4 acc4 = nsx[mt];   // C-init = -s_a (registers, no load)
                acc4 = __builtin_amdgcn_mfma_f32_16x16x32_bf16(af[mt][0], b0, acc4, 0, 0, 0);
                acc4 = __builtin_amdgcn_mfma_f32_16x16x32_bf16(af[mt][1], b1, acc4, 0, 0, 0);

                if (sym && jt == it) {
                    // diagonal tile: count only j > i (trace excluded exactly)
#pragma unroll
                    for (int r = 0; r < 4; ++r) {
                        float v = exp2_fast(acc4[r] - syv);
                        lsum += (l15 > quad * 4 + r) ? v : 0.0f;
                    }
                } else {
#pragma unroll
                    for (int r = 0; r < 4; ++r)
                        lsum += exp2_fast(acc4[r] - syv);
                }
            }
        }
    }

    // wave reduce
#pragma unroll
    for (int off = 32; off; off >>= 1) lsum += __shfl_xor(lsum, off, 64);

    __shared__ float ws4[4];
    if (lane == 0) ws4[wid] = lsum;
    __syncthreads();
    if (tid == 0) {
        double tot = (double)ws4[0] + (double)ws4[1] + (double)ws4[2] + (double)ws4[3];
        // sym coefficient folds the x2 for sum_{i!=j} = 2 * sum_{j>i}
        const double c = sym ? (2.0 / (8192.0 * 8191.0))
                             : (-2.0 / (8192.0 * 8192.0));
        if (tot != 0.0) atomicAdd(acc, tot * c);
        __threadfence();
        unsigned done = atomicAdd(cnt, 1u);
        if (done == TOTAL_MAIN_BLOCKS - 1) {
            __threadfence();
            double v = *(volatile double*)acc;   // all adds visible: we're last
            out[0] = (float)(v > 0.0 ? v : 0.0);
        }
    }
}

// ---------------------------------------------------------------------------
extern "C" void kernel_launch(void* const* d_in, const int* in_sizes, int n_in,
                              void* d_out, int out_size, void* d_ws, size_t ws_size,
                              hipStream_t stream) {
    const float* z_seq   = (const float*)d_in[0];   // [16,512,64]
    const float* pmean   = (const float*)d_in[1];   // [64]
    const float* pstd    = (const float*)d_in[2];   // [64]
    const float* z_prior = (const float*)d_in[3];   // [8192,64]
    float* out = (float*)d_out;

    char* ws = (char*)d_ws;
    __hip_bfloat16* Xb = (__hip_bfloat16*)(ws);                    // 1 MB
    __hip_bfloat16* Yb = (__hip_bfloat16*)(ws + (1u << 20));       // 1 MB
    float* sxx = (float*)(ws + (2u << 20));                        // 32 KB
    float* syy = (float*)(ws + (2u << 20) + 32768);                // 32 KB
    double* acc = (double*)(ws + (2u << 20) + 65536);              // 8 B
    unsigned* cnt = (unsigned*)(ws + (2u << 20) + 65536 + 64);     // 4 B

    mmd_prep<<<dim3(1024), dim3(256), 0, stream>>>(
        z_seq, pmean, pstd, z_prior, Xb, Yb, sxx, syy, acc, cnt);
    mmd_main<<<dim3(32, 64, 3), dim3(256), 0, stream>>>(
        Xb, Yb, sxx, syy, acc, cnt, out);
}

// Round 5
// 139.827 us; speedup vs baseline: 3.0625x; 1.4126x over previous
//
#include <hip/hip_runtime.h>
#include <hip/hip_bf16.h>

// ---------------------------------------------------------------------------
// MMD loss:  mmd = 2*Sxx_upper/(n(n-1)) + 2*Syy_upper/(m(m-1)) - 2*Sxy/(n*m)
// k(a,b) = exp(-|a-b|^2 / 128)  (sigma^2 = D = 64), N = M = 8192, D = 64.
//
// Algebra: store A' = A * sqrt(log2e)/8 in bf16 and s = 0.5*|a'|^2 (f32).
// Then  exp(-|a-b|^2/128) = exp2( dot(a',b') - s_a - s_b ).
// MFMA C-init = -s_a (register data), post-MFMA: sub(s_b), v_exp, accumulate.
//
// Hard-won structure lessons (R0..R4):
//  - default __launch_bounds__(256) ONLY. (256,8) -> compiler spills to
//    scratch (203MB writes, 373us). No cap -> 40-44 VGPR, best.
//  - runtime `sym` + in-loop guards keep the scheduler from ballooning
//    registers (templated straight-line body hit 108 VGPR / 2x time).
//  - NO single-address atomic finalize: 6144 blocks x (f64 atomicAdd +
//    threadfence + u32 atomicAdd) on one line serialize ~65us of idle tail
//    (R1: 154us, R4: 146us vs R0: 81us). Per-block partials[] + a tiny
//    third kernel is ~60us faster.
//  - compute phase (~81us) is latency/stall-bound, NOT VALU-issue-bound.
// ---------------------------------------------------------------------------

using short8  = __attribute__((ext_vector_type(8))) short;  // 8 bf16 (4 VGPRs)
using f32x4   = __attribute__((ext_vector_type(4))) float;  // 4 fp32
using float4v = __attribute__((ext_vector_type(4))) float;

#define NROWS 8192
#define DDIM  64
#define TOTAL_MAIN_BLOCKS (32 * 64 * 3)

// sqrt(log2(e)) / 8
#define PRESCALE 0.15014030109830622f

__device__ __forceinline__ float exp2_fast(float x) {
#if __has_builtin(__builtin_amdgcn_exp2f)
    return __builtin_amdgcn_exp2f(x);
#else
    return exp2f(x);
#endif
}

// ---------------------------------------------------------------------------
// Prep: normalize X, prescale, cast X/Y to bf16, compute s = 0.5*|row'|^2
// from the bf16-rounded values (consistent with the MFMA inputs).
// 4 rows per wave, float4 loads.
// ---------------------------------------------------------------------------
__global__ __launch_bounds__(256) void mmd_prep(
    const float* __restrict__ z_seq, const float* __restrict__ pmean,
    const float* __restrict__ pstd, const float* __restrict__ z_prior,
    __hip_bfloat16* __restrict__ Xb, __hip_bfloat16* __restrict__ Yb,
    float* __restrict__ sxx, float* __restrict__ syy)
{
    const int tid  = threadIdx.x;
    const int lane = tid & 63;
    const int wid  = tid >> 6;
    const int w    = blockIdx.x * 4 + wid;       // wave id, 0..4095
    const int sub  = lane >> 4;                  // row within wave, 0..3
    const int row  = w * 4 + sub;                // 0..16383
    const int d0   = (lane & 15) * 4;            // dim offset, 0..60

    float4v v;
    __hip_bfloat16* dst;
    float* sdst;
    int r;
    if (row < NROWS) {
        r = row;
        float4v z  = *reinterpret_cast<const float4v*>(z_seq + (size_t)r * DDIM + d0);
        float4v pm = *reinterpret_cast<const float4v*>(pmean + d0);
        float4v ps = *reinterpret_cast<const float4v*>(pstd + d0);
#pragma unroll
        for (int k = 0; k < 4; ++k) v[k] = (z[k] - pm[k]) / ps[k];
        dst = Xb; sdst = sxx;
    } else {
        r = row - NROWS;
        v = *reinterpret_cast<const float4v*>(z_prior + (size_t)r * DDIM + d0);
        dst = Yb; sdst = syy;
    }

    ushort4 hb;
    float sq = 0.0f;
#pragma unroll
    for (int k = 0; k < 4; ++k) {
        __hip_bfloat16 b = __float2bfloat16(v[k] * PRESCALE);
        reinterpret_cast<__hip_bfloat16*>(&hb)[k] = b;
        float vb = __bfloat162float(b);
        sq += vb * vb;
    }
    *reinterpret_cast<ushort4*>(dst + (size_t)r * DDIM + d0) = hb;

    // reduce across the 16 lanes of this row-group (xor<16 stays in group)
#pragma unroll
    for (int off = 8; off; off >>= 1) sq += __shfl_xor(sq, off, 64);
    if ((lane & 15) == 0) sdst[r] = 0.5f * sq;
}

// ---------------------------------------------------------------------------
// Main: grid (32 jblocks, 64 iblocks, 3 modes). Block tile 128(i) x 256(j),
// 4 waves in 2x2, wave tile 64x128.  mode 0: XX (sym), 1: YY (sym), 2: XY.
// Each block writes one double partial (raw sum; coefficients in finalize).
// ---------------------------------------------------------------------------
__global__ __launch_bounds__(256) void mmd_main(
    const __hip_bfloat16* __restrict__ Xb, const __hip_bfloat16* __restrict__ Yb,
    const float* __restrict__ sxx, const float* __restrict__ syy,
    double* __restrict__ partials)
{
    const int mode = blockIdx.z;
    const int bj = blockIdx.x;          // 0..31  (256-wide j blocks)
    const int bi = blockIdx.y;          // 0..63  (128-tall i blocks)
    const int bid = mode * 2048 + bi * 32 + bj;

    const __hip_bfloat16* A;
    const __hip_bfloat16* Bp;
    const float* sa;
    const float* sb;
    if (mode == 0)      { A = Xb; Bp = Xb; sa = sxx; sb = sxx; }
    else if (mode == 1) { A = Yb; Bp = Yb; sa = syy; sb = syy; }
    else                { A = Xb; Bp = Yb; sa = sxx; sb = syy; }
    const bool sym = (mode < 2);

    const int tid  = threadIdx.x;
    const int lane = tid & 63;
    const int wid  = tid >> 6;
    const int quad = lane >> 4;
    const int l15  = lane & 15;

    const int iBlock = bi * 128;
    const int jBlock = bj * 256;

    // entire block strictly below the diagonal -> nothing to do
    if (sym && (jBlock + 256 <= iBlock)) {
        if (tid == 0) partials[bid] = 0.0;
        return;
    }

    const int i0 = iBlock + (wid >> 1) * 64;   // wave row origin
    const int j0 = jBlock + (wid & 1) * 128;   // wave col origin

    // Persistent A fragments + negated row half-norms (MFMA C-init).
    short8 af[4][2];
    f32x4  nsx[4];
#pragma unroll
    for (int mt = 0; mt < 4; ++mt) {
        const int ar = i0 + mt * 16 + l15;
#pragma unroll
        for (int ks = 0; ks < 2; ++ks)
            af[mt][ks] = *reinterpret_cast<const short8*>(
                A + (size_t)ar * DDIM + ks * 32 + quad * 8);
        f32x4 s4 = *reinterpret_cast<const f32x4*>(sa + i0 + mt * 16 + quad * 4);
        nsx[mt] = -s4;
    }

    const __hip_bfloat16* bbase = Bp + (size_t)(j0 + l15) * DDIM + quad * 8;

    float lsum = 0.0f;

#pragma unroll
    for (int nt = 0; nt < 8; ++nt) {
        const int jt = j0 + nt * 16;
        if (sym && jt < i0) continue;    // all 4 mt-tiles below diagonal

        const __hip_bfloat16* bp = bbase + (size_t)nt * 16 * DDIM;
        short8 b0 = *reinterpret_cast<const short8*>(bp);
        short8 b1 = *reinterpret_cast<const short8*>(bp + 32);
        const float syv = sb[jt + l15];  // col half-norm (post-MFMA use)

#pragma unroll
        for (int mt = 0; mt < 4; ++mt) {
            const int it = i0 + mt * 16;
            if (sym && jt < it) continue;          // tile strictly below diag

            f32x4 acc4 = nsx[mt];   // C-init = -s_a (registers, no load)
            acc4 = __builtin_amdgcn_mfma_f32_16x16x32_bf16(af[mt][0], b0, acc4, 0, 0, 0);
            acc4 = __builtin_amdgcn_mfma_f32_16x16x32_bf16(af[mt][1], b1, acc4, 0, 0, 0);

            if (sym && jt == it) {
                // diagonal tile: count only j > i (trace excluded exactly)
#pragma unroll
                for (int r = 0; r < 4; ++r) {
                    float v = exp2_fast(acc4[r] - syv);
                    lsum += (l15 > quad * 4 + r) ? v : 0.0f;
                }
            } else {
#pragma unroll
                for (int r = 0; r < 4; ++r)
                    lsum += exp2_fast(acc4[r] - syv);
            }
        }
    }

    // wave reduce
#pragma unroll
    for (int off = 32; off; off >>= 1) lsum += __shfl_xor(lsum, off, 64);

    __shared__ float ws4[4];
    if (lane == 0) ws4[wid] = lsum;
    __syncthreads();
    if (tid == 0) {
        double tot = (double)ws4[0] + (double)ws4[1] + (double)ws4[2] + (double)ws4[3];
        partials[bid] = tot;
    }
}

// ---------------------------------------------------------------------------
// Finalize: reduce 6144 block partials with per-mode coefficients.
// sym coefficient folds the x2 for sum_{i!=j} = 2 * sum_{j>i}.
// ---------------------------------------------------------------------------
__global__ __launch_bounds__(256) void mmd_final(
    const double* __restrict__ partials, float* __restrict__ out)
{
    const int tid = threadIdx.x;
    const double cs = 2.0 / (8192.0 * 8191.0);       // modes 0,1
    const double cx = -2.0 / (8192.0 * 8192.0);      // mode 2

    double s = 0.0;
    for (int idx = tid; idx < TOTAL_MAIN_BLOCKS; idx += 256) {
        double c = (idx < 4096) ? cs : cx;
        s += partials[idx] * c;
    }
#pragma unroll
    for (int off = 32; off; off >>= 1) s += __shfl_xor(s, off, 64);

    __shared__ double wsum[4];
    const int lane = tid & 63, wid = tid >> 6;
    if (lane == 0) wsum[wid] = s;
    __syncthreads();
    if (tid == 0) {
        double mmd = wsum[0] + wsum[1] + wsum[2] + wsum[3];
        out[0] = (float)(mmd > 0.0 ? mmd : 0.0);
    }
}

// ---------------------------------------------------------------------------
extern "C" void kernel_launch(void* const* d_in, const int* in_sizes, int n_in,
                              void* d_out, int out_size, void* d_ws, size_t ws_size,
                              hipStream_t stream) {
    const float* z_seq   = (const float*)d_in[0];   // [16,512,64]
    const float* pmean   = (const float*)d_in[1];   // [64]
    const float* pstd    = (const float*)d_in[2];   // [64]
    const float* z_prior = (const float*)d_in[3];   // [8192,64]
    float* out = (float*)d_out;

    char* ws = (char*)d_ws;
    __hip_bfloat16* Xb = (__hip_bfloat16*)(ws);                    // 1 MB
    __hip_bfloat16* Yb = (__hip_bfloat16*)(ws + (1u << 20));       // 1 MB
    float* sxx = (float*)(ws + (2u << 20));                        // 32 KB
    float* syy = (float*)(ws + (2u << 20) + 32768);                // 32 KB
    double* partials = (double*)(ws + (2u << 20) + 65536);         // 48 KB

    mmd_prep<<<dim3(1024), dim3(256), 0, stream>>>(
        z_seq, pmean, pstd, z_prior, Xb, Yb, sxx, syy);
    mmd_main<<<dim3(32, 64, 3), dim3(256), 0, stream>>>(
        Xb, Yb, sxx, syy, partials);
    mmd_final<<<dim3(1), dim3(256), 0, stream>>>(partials, out);
}

// Round 6
// 119.247 us; speedup vs baseline: 3.5910x; 1.1726x over previous
//
#include <hip/hip_runtime.h>
#include <hip/hip_bf16.h>
#include <math.h>

// ---------------------------------------------------------------------------
// MMD loss:  mmd = 2*Sxx_upper/(n(n-1)) + 2*Syy_upper/(m(m-1)) - 2*Sxy/(n*m)
// k(a,b) = exp(-|a-b|^2 / 128)  (sigma^2 = D = 64), N = M = 8192, D = 64.
//
// Algebra: store A' = A * sqrt(log2e)/8 in bf16 and s = 0.5*|a'|^2 (f32).
// Then  exp(-|a-b|^2/128) = exp2( dot(a',b') - s_a - s_b ).
// MFMA C-init = nsx + nsy (both register-resident, prologue-loaded), so the
// per-element epilogue is just v_exp + v_add.
//
// Hard-won structure lessons (R0..R5):
//  - default __launch_bounds__(256) ONLY. (256,8) -> compiler spills to
//    scratch (203MB writes, 373us). No cap -> ~40-64 VGPR, best.
//  - runtime `sym` + in-loop guards keep the scheduler from ballooning
//    registers (templated straight-line body hit 108 VGPR / 2x time in R1).
//  - NO single-address atomic finalize (6144 RMWs on one line = ~65us tail).
//    Per-block partials[] + tiny third kernel (R5: 146 -> 79us main).
//  - compute phase is latency/stall-bound (VALU 36%, issue floor ~15us):
//    R6 adds compact balance-ordered grid + 1-deep B-register rotation
//    (+8 VGPR, target <=64) + nsy-hoisted C-init.
// ---------------------------------------------------------------------------

using short8  = __attribute__((ext_vector_type(8))) short;  // 8 bf16 (4 VGPRs)
using f32x4   = __attribute__((ext_vector_type(4))) float;  // 4 fp32
using float4v = __attribute__((ext_vector_type(4))) float;

#define NROWS 8192
#define DDIM  64
// Active blocks only: 2048 XY (dispatched first) + 2*1056 sym-upper.
#define GRID_MAIN (2048 + 2 * 1056)

// sqrt(log2(e)) / 8
#define PRESCALE 0.15014030109830622f

__device__ __forceinline__ float exp2_fast(float x) {
#if __has_builtin(__builtin_amdgcn_exp2f)
    return __builtin_amdgcn_exp2f(x);
#else
    return exp2f(x);
#endif
}

// ---------------------------------------------------------------------------
// Prep: normalize X, prescale, cast X/Y to bf16, compute s = 0.5*|row'|^2
// from the bf16-rounded values (consistent with the MFMA inputs).
// 4 rows per wave, float4 loads.
// ---------------------------------------------------------------------------
__global__ __launch_bounds__(256) void mmd_prep(
    const float* __restrict__ z_seq, const float* __restrict__ pmean,
    const float* __restrict__ pstd, const float* __restrict__ z_prior,
    __hip_bfloat16* __restrict__ Xb, __hip_bfloat16* __restrict__ Yb,
    float* __restrict__ sxx, float* __restrict__ syy)
{
    const int tid  = threadIdx.x;
    const int lane = tid & 63;
    const int wid  = tid >> 6;
    const int w    = blockIdx.x * 4 + wid;       // wave id, 0..4095
    const int sub  = lane >> 4;                  // row within wave, 0..3
    const int row  = w * 4 + sub;                // 0..16383
    const int d0   = (lane & 15) * 4;            // dim offset, 0..60

    float4v v;
    __hip_bfloat16* dst;
    float* sdst;
    int r;
    if (row < NROWS) {
        r = row;
        float4v z  = *reinterpret_cast<const float4v*>(z_seq + (size_t)r * DDIM + d0);
        float4v pm = *reinterpret_cast<const float4v*>(pmean + d0);
        float4v ps = *reinterpret_cast<const float4v*>(pstd + d0);
#pragma unroll
        for (int k = 0; k < 4; ++k) v[k] = (z[k] - pm[k]) / ps[k];
        dst = Xb; sdst = sxx;
    } else {
        r = row - NROWS;
        v = *reinterpret_cast<const float4v*>(z_prior + (size_t)r * DDIM + d0);
        dst = Yb; sdst = syy;
    }

    ushort4 hb;
    float sq = 0.0f;
#pragma unroll
    for (int k = 0; k < 4; ++k) {
        __hip_bfloat16 b = __float2bfloat16(v[k] * PRESCALE);
        reinterpret_cast<__hip_bfloat16*>(&hb)[k] = b;
        float vb = __bfloat162float(b);
        sq += vb * vb;
    }
    *reinterpret_cast<ushort4*>(dst + (size_t)r * DDIM + d0) = hb;

    // reduce across the 16 lanes of this row-group (xor<16 stays in group)
#pragma unroll
    for (int off = 8; off; off >>= 1) sq += __shfl_xor(sq, off, 64);
    if ((lane & 15) == 0) sdst[r] = 0.5f * sq;
}

// ---------------------------------------------------------------------------
// Main: compact 1-D grid of ACTIVE blocks only.
//   bid <  2048            : XY block, bi = bid>>5 (0..63), bj = bid&31.
//   bid >= 2048            : t = bid-2048; sym mode = t&1 (0:XX, 1:YY);
//                            u = t>>1 in [0,1056) enumerates upper blocks:
//                            bj from u in [bj(bj+1), (bj+1)(bj+2)), bi = rest.
// Block tile 128(i) x 256(j), 4 waves in 2x2, wave tile 64x128.
// B fragments rotate one nt ahead (ILP); C-init = nsx + nsy (registers).
// Each block writes one double partial (raw sum; coefficients in finalize).
// ---------------------------------------------------------------------------
__global__ __launch_bounds__(256) void mmd_main(
    const __hip_bfloat16* __restrict__ Xb, const __hip_bfloat16* __restrict__ Yb,
    const float* __restrict__ sxx, const float* __restrict__ syy,
    double* __restrict__ partials)
{
    const int bid = blockIdx.x;

    int bi, bj;
    bool sym;
    const __hip_bfloat16* A;
    const __hip_bfloat16* Bp;
    const float* sa;
    const float* sb;

    if (bid < 2048) {                       // XY: heavy, uniform, FIRST
        sym = false;
        bi = bid >> 5; bj = bid & 31;
        A = Xb; Bp = Yb; sa = sxx; sb = syy;
    } else {                                // sym upper-triangle blocks
        sym = true;
        const int t = bid - 2048;
        const int u = t >> 1;
        int b = (int)((sqrtf((float)(4 * u + 1)) - 1.0f) * 0.5f);
        while ((b + 1) * (b + 2) <= u) ++b; // integer fixup of float sqrt
        while (b * (b + 1) > u) --b;
        bj = b;
        bi = u - b * (b + 1);               // 0 .. 2bj+1  (upper incl. diag)
        if (t & 1) { A = Yb; Bp = Yb; sa = syy; sb = syy; }
        else       { A = Xb; Bp = Xb; sa = sxx; sb = sxx; }
    }

    const int tid  = threadIdx.x;
    const int lane = tid & 63;
    const int wid  = tid >> 6;
    const int quad = lane >> 4;
    const int l15  = lane & 15;

    const int iBlock = bi * 128;
    const int jBlock = bj * 256;

    const int i0 = iBlock + (wid >> 1) * 64;   // wave row origin
    const int j0 = jBlock + (wid & 1) * 128;   // wave col origin

    // Persistent A fragments + negated row half-norms.
    short8 af[4][2];
    f32x4  nsx[4];
#pragma unroll
    for (int mt = 0; mt < 4; ++mt) {
        const int ar = i0 + mt * 16 + l15;
#pragma unroll
        for (int ks = 0; ks < 2; ++ks)
            af[mt][ks] = *reinterpret_cast<const short8*>(
                A + (size_t)ar * DDIM + ks * 32 + quad * 8);
        f32x4 s4 = *reinterpret_cast<const f32x4*>(sa + i0 + mt * 16 + quad * 4);
        nsx[mt] = -s4;
    }

    // Hoisted negated column half-norms for this lane's 8 j-tiles
    // (prologue-issued: never on the MFMA dependency chain).
    float nsy[8];
#pragma unroll
    for (int nt = 0; nt < 8; ++nt) nsy[nt] = -sb[j0 + l15 + nt * 16];

    const __hip_bfloat16* bbase = Bp + (size_t)(j0 + l15) * DDIM + quad * 8;

    // B rotation: b0/b1 hold tile nt; p0/p1 prefetch nt+1.
    short8 b0 = *reinterpret_cast<const short8*>(bbase);
    short8 b1 = *reinterpret_cast<const short8*>(bbase + 32);

    float lsum = 0.0f;

#pragma unroll
    for (int nt = 0; nt < 8; ++nt) {
        short8 p0, p1;
        if (nt < 7) {
            const __hip_bfloat16* np = bbase + (size_t)(nt + 1) * 16 * DDIM;
            p0 = *reinterpret_cast<const short8*>(np);
            p1 = *reinterpret_cast<const short8*>(np + 32);
        }

        const int jt = j0 + nt * 16;
        if (!sym || jt >= i0) {
#pragma unroll
            for (int mt = 0; mt < 4; ++mt) {
                const int it = i0 + mt * 16;
                if (sym && jt < it) continue;      // tile strictly below diag

                f32x4 acc4;
#pragma unroll
                for (int r = 0; r < 4; ++r) acc4[r] = nsx[mt][r] + nsy[nt];
                acc4 = __builtin_amdgcn_mfma_f32_16x16x32_bf16(af[mt][0], b0, acc4, 0, 0, 0);
                acc4 = __builtin_amdgcn_mfma_f32_16x16x32_bf16(af[mt][1], b1, acc4, 0, 0, 0);

                if (sym && jt == it) {
                    // diagonal tile: count only j > i (trace excluded exactly)
#pragma unroll
                    for (int r = 0; r < 4; ++r) {
                        float v = exp2_fast(acc4[r]);
                        lsum += (l15 > quad * 4 + r) ? v : 0.0f;
                    }
                } else {
#pragma unroll
                    for (int r = 0; r < 4; ++r)
                        lsum += exp2_fast(acc4[r]);
                }
            }
        }

        if (nt < 7) { b0 = p0; b1 = p1; }
    }

    // wave reduce
#pragma unroll
    for (int off = 32; off; off >>= 1) lsum += __shfl_xor(lsum, off, 64);

    __shared__ float ws4[4];
    if (lane == 0) ws4[wid] = lsum;
    __syncthreads();
    if (tid == 0) {
        double tot = (double)ws4[0] + (double)ws4[1] + (double)ws4[2] + (double)ws4[3];
        partials[bid] = tot;
    }
}

// ---------------------------------------------------------------------------
// Finalize: reduce GRID_MAIN block partials with per-mode coefficients.
// bid < 2048 -> XY (negative coeff); else sym (x2 folds sum_{i!=j}).
// ---------------------------------------------------------------------------
__global__ __launch_bounds__(256) void mmd_final(
    const double* __restrict__ partials, float* __restrict__ out)
{
    const int tid = threadIdx.x;
    const double cs = 2.0 / (8192.0 * 8191.0);       // sym modes
    const double cx = -2.0 / (8192.0 * 8192.0);      // XY

    double s = 0.0;
    for (int idx = tid; idx < GRID_MAIN; idx += 256) {
        double c = (idx < 2048) ? cx : cs;
        s += partials[idx] * c;
    }
#pragma unroll
    for (int off = 32; off; off >>= 1) s += __shfl_xor(s, off, 64);

    __shared__ double wsum[4];
    const int lane = tid & 63, wid = tid >> 6;
    if (lane == 0) wsum[wid] = s;
    __syncthreads();
    if (tid == 0) {
        double mmd = wsum[0] + wsum[1] + wsum[2] + wsum[3];
        out[0] = (float)(mmd > 0.0 ? mmd : 0.0);
    }
}

// ---------------------------------------------------------------------------
extern "C" void kernel_launch(void* const* d_in, const int* in_sizes, int n_in,
                              void* d_out, int out_size, void* d_ws, size_t ws_size,
                              hipStream_t stream) {
    const float* z_seq   = (const float*)d_in[0];   // [16,512,64]
    const float* pmean   = (const float*)d_in[1];   // [64]
    const float* pstd    = (const float*)d_in[2];   // [64]
    const float* z_prior = (const float*)d_in[3];   // [8192,64]
    float* out = (float*)d_out;

    char* ws = (char*)d_ws;
    __hip_bfloat16* Xb = (__hip_bfloat16*)(ws);                    // 1 MB
    __hip_bfloat16* Yb = (__hip_bfloat16*)(ws + (1u << 20));       // 1 MB
    float* sxx = (float*)(ws + (2u << 20));                        // 32 KB
    float* syy = (float*)(ws + (2u << 20) + 32768);                // 32 KB
    double* partials = (double*)(ws + (2u << 20) + 65536);         // ~33 KB

    mmd_prep<<<dim3(1024), dim3(256), 0, stream>>>(
        z_seq, pmean, pstd, z_prior, Xb, Yb, sxx, syy);
    mmd_main<<<dim3(GRID_MAIN), dim3(256), 0, stream>>>(
        Xb, Yb, sxx, syy, partials);
    mmd_final<<<dim3(1), dim3(256), 0, stream>>>(partials, out);
}

// Round 7
// 101.729 us; speedup vs baseline: 4.2094x; 1.1722x over previous
//
#include <hip/hip_runtime.h>
#include <hip/hip_bf16.h>
#include <math.h>

// ---------------------------------------------------------------------------
// MMD loss:  mmd = 2*Sxx_upper/(n(n-1)) + 2*Syy_upper/(m(m-1)) - 2*Sxy/(n*m)
// k(a,b) = exp(-|a-b|^2 / 128)  (sigma^2 = D = 64), N = M = 8192, D = 64.
//
// Algebra: store A' = A * sqrt(log2e)/8 in bf16 and s = 0.5*|a'|^2 (f32).
// Then  exp(-|a-b|^2/128) = exp2( dot(a',b') - s_a - s_b ).
// MFMA C-init = nsx + nsy (register-resident, prologue-loaded).
//
// Hard-won structure lessons (R0..R6):
//  - default __launch_bounds__(256) ONLY. (256,8) -> compiler spills (373us).
//  - runtime `sym` + in-loop guards keep regs in check (R1: 108 VGPR, 2x).
//  - NO single-address atomic finalize (~65us serialized tail, R1/R4).
//  - compact balance-ordered grid + prologue-hoisted norms: R6, 79->56us.
//  - R7: B panel staged to LDS once per block (32KB) via global_load_lds,
//    XOR-swizzled both sides (f(x)=x^(((x>>7)&7)<<4), involution) to kill
//    the stride-128B 16-way bank conflict. Inner loop has ZERO global loads.
// ---------------------------------------------------------------------------

using short8  = __attribute__((ext_vector_type(8))) short;  // 8 bf16 (4 VGPRs)
using f32x4   = __attribute__((ext_vector_type(4))) float;  // 4 fp32
using float4v = __attribute__((ext_vector_type(4))) float;

#define NROWS 8192
#define DDIM  64
// Active blocks only: 2048 XY (dispatched first) + 2*1056 sym-upper.
#define GRID_MAIN (2048 + 2 * 1056)

// sqrt(log2(e)) / 8
#define PRESCALE 0.15014030109830622f

__device__ __forceinline__ float exp2_fast(float x) {
#if __has_builtin(__builtin_amdgcn_exp2f)
    return __builtin_amdgcn_exp2f(x);
#else
    return exp2f(x);
#endif
}

// ---------------------------------------------------------------------------
// Prep: normalize X, prescale, cast X/Y to bf16, compute s = 0.5*|row'|^2
// from the bf16-rounded values. 4 rows per wave, float4 loads. (R6-proven.)
// ---------------------------------------------------------------------------
__global__ __launch_bounds__(256) void mmd_prep(
    const float* __restrict__ z_seq, const float* __restrict__ pmean,
    const float* __restrict__ pstd, const float* __restrict__ z_prior,
    __hip_bfloat16* __restrict__ Xb, __hip_bfloat16* __restrict__ Yb,
    float* __restrict__ sxx, float* __restrict__ syy)
{
    const int tid  = threadIdx.x;
    const int lane = tid & 63;
    const int wid  = tid >> 6;
    const int w    = blockIdx.x * 4 + wid;       // wave id, 0..4095
    const int sub  = lane >> 4;                  // row within wave, 0..3
    const int row  = w * 4 + sub;                // 0..16383
    const int d0   = (lane & 15) * 4;            // dim offset, 0..60

    float4v v;
    __hip_bfloat16* dst;
    float* sdst;
    int r;
    if (row < NROWS) {
        r = row;
        float4v z  = *reinterpret_cast<const float4v*>(z_seq + (size_t)r * DDIM + d0);
        float4v pm = *reinterpret_cast<const float4v*>(pmean + d0);
        float4v ps = *reinterpret_cast<const float4v*>(pstd + d0);
#pragma unroll
        for (int k = 0; k < 4; ++k) v[k] = (z[k] - pm[k]) / ps[k];
        dst = Xb; sdst = sxx;
    } else {
        r = row - NROWS;
        v = *reinterpret_cast<const float4v*>(z_prior + (size_t)r * DDIM + d0);
        dst = Yb; sdst = syy;
    }

    ushort4 hb;
    float sq = 0.0f;
#pragma unroll
    for (int k = 0; k < 4; ++k) {
        __hip_bfloat16 b = __float2bfloat16(v[k] * PRESCALE);
        reinterpret_cast<__hip_bfloat16*>(&hb)[k] = b;
        float vb = __bfloat162float(b);
        sq += vb * vb;
    }
    *reinterpret_cast<ushort4*>(dst + (size_t)r * DDIM + d0) = hb;

    // reduce across the 16 lanes of this row-group (xor<16 stays in group)
#pragma unroll
    for (int off = 8; off; off >>= 1) sq += __shfl_xor(sq, off, 64);
    if ((lane & 15) == 0) sdst[r] = 0.5f * sq;
}

// ---------------------------------------------------------------------------
// Main: compact 1-D grid of ACTIVE blocks only.
//   bid <  2048 : XY block, bi = bid>>5 (0..63), bj = bid&31.
//   bid >= 2048 : t = bid-2048; sym mode = t&1 (0:XX, 1:YY);
//                 u = t>>1 in [0,1056) -> (bj, bi) upper-triangle decode.
// Block tile 128(i) x 256(j), 4 waves in 2x2, wave tile 64x128.
// B panel (256x64 bf16 = 32KB) staged to LDS once, XOR-swizzled; inner loop
// is ds_read_b128 + MFMA + exp2 only.
// ---------------------------------------------------------------------------
__global__ __launch_bounds__(256) void mmd_main(
    const __hip_bfloat16* __restrict__ Xb, const __hip_bfloat16* __restrict__ Yb,
    const float* __restrict__ sxx, const float* __restrict__ syy,
    double* __restrict__ partials)
{
    __shared__ __align__(16) char Bs[32768];     // 256 cols x 128 B

    const int bid = blockIdx.x;

    int bi, bj;
    bool sym;
    const __hip_bfloat16* A;
    const __hip_bfloat16* Bp;
    const float* sa;
    const float* sb;

    if (bid < 2048) {                       // XY: heavy, uniform, FIRST
        sym = false;
        bi = bid >> 5; bj = bid & 31;
        A = Xb; Bp = Yb; sa = sxx; sb = syy;
    } else {                                // sym upper-triangle blocks
        sym = true;
        const int t = bid - 2048;
        const int u = t >> 1;
        int b = (int)((sqrtf((float)(4 * u + 1)) - 1.0f) * 0.5f);
        while ((b + 1) * (b + 2) <= u) ++b; // integer fixup of float sqrt
        while (b * (b + 1) > u) --b;
        bj = b;
        bi = u - b * (b + 1);               // 0 .. 2bj+1  (upper incl. diag)
        if (t & 1) { A = Yb; Bp = Yb; sa = syy; sb = syy; }
        else       { A = Xb; Bp = Xb; sa = sxx; sb = sxx; }
    }

    const int tid  = threadIdx.x;
    const int lane = tid & 63;
    const int wid  = tid >> 6;
    const int quad = lane >> 4;
    const int l15  = lane & 15;

    const int iBlock = bi * 128;
    const int jBlock = bj * 256;

    // ---- Stage B panel -> LDS, source pre-swizzled with f(x)=x^(((x>>7)&7)<<4)
    // so that a swizzled read is conflict-free (2-way max).  Lane l of chunk c
    // writes LDS[c*1024 + l*16] <- B[f(c*1024 + l*16)].
    {
        const char* gB = (const char*)Bp + (size_t)jBlock * 128;
#pragma unroll
        for (int k = 0; k < 8; ++k) {
            const int c  = wid * 8 + k;
            const int x  = c * 1024 + lane * 16;
            const int gx = x ^ (((x >> 7) & 7) << 4);
            __builtin_amdgcn_global_load_lds(
                (const __attribute__((address_space(1))) void*)(gB + gx),
                (__attribute__((address_space(3))) void*)(Bs + c * 1024),
                16, 0, 0);
        }
    }

    const int i0 = iBlock + (wid >> 1) * 64;   // wave row origin
    const int j0 = jBlock + (wid & 1) * 128;   // wave col origin

    // Persistent A fragments + negated row half-norms (overlaps LDS staging).
    short8 af[4][2];
    f32x4  nsx[4];
#pragma unroll
    for (int mt = 0; mt < 4; ++mt) {
        const int ar = i0 + mt * 16 + l15;
#pragma unroll
        for (int ks = 0; ks < 2; ++ks)
            af[mt][ks] = *reinterpret_cast<const short8*>(
                A + (size_t)ar * DDIM + ks * 32 + quad * 8);
        f32x4 s4 = *reinterpret_cast<const f32x4*>(sa + i0 + mt * 16 + quad * 4);
        nsx[mt] = -s4;
    }

    // Hoisted negated column half-norms for this lane's 8 j-tiles.
    float nsy[8];
#pragma unroll
    for (int nt = 0; nt < 8; ++nt) nsy[nt] = -sb[j0 + l15 + nt * 16];

    __syncthreads();   // staging complete (compiler drains vmcnt first)

    // Per-lane constant swizzle for reads: col&7 == l15&7 (col = 128w+16nt+l15).
    const int swz   = (l15 & 7) << 4;
    const int off0  = (quad * 16) ^ swz;          // ks=0 in-col byte offset
    const int off1  = (quad * 16 + 64) ^ swz;     // ks=1 in-col byte offset
    const char* lb0 = Bs + ((wid & 1) * 128 + l15) * 128;

    float lsum = 0.0f;

#pragma unroll
    for (int nt = 0; nt < 8; ++nt) {
        const int jt = j0 + nt * 16;
        if (sym && jt < i0) continue;    // all 4 mt-tiles below diagonal

        const char* lp = lb0 + nt * 16 * 128;
        short8 b0 = *reinterpret_cast<const short8*>(lp + off0);
        short8 b1 = *reinterpret_cast<const short8*>(lp + off1);

#pragma unroll
        for (int mt = 0; mt < 4; ++mt) {
            const int it = i0 + mt * 16;
            if (sym && jt < it) continue;      // tile strictly below diag

            f32x4 acc4;
#pragma unroll
            for (int r = 0; r < 4; ++r) acc4[r] = nsx[mt][r] + nsy[nt];
            acc4 = __builtin_amdgcn_mfma_f32_16x16x32_bf16(af[mt][0], b0, acc4, 0, 0, 0);
            acc4 = __builtin_amdgcn_mfma_f32_16x16x32_bf16(af[mt][1], b1, acc4, 0, 0, 0);

            if (sym && jt == it) {
                // diagonal tile: count only j > i (trace excluded exactly)
#pragma unroll
                for (int r = 0; r < 4; ++r) {
                    float v = exp2_fast(acc4[r]);
                    lsum += (l15 > quad * 4 + r) ? v : 0.0f;
                }
            } else {
#pragma unroll
                for (int r = 0; r < 4; ++r)
                    lsum += exp2_fast(acc4[r]);
            }
        }
    }

    // wave reduce
#pragma unroll
    for (int off = 32; off; off >>= 1) lsum += __shfl_xor(lsum, off, 64);

    __shared__ float ws4[4];
    if (lane == 0) ws4[wid] = lsum;
    __syncthreads();
    if (tid == 0) {
        double tot = (double)ws4[0] + (double)ws4[1] + (double)ws4[2] + (double)ws4[3];
        partials[bid] = tot;
    }
}

// ---------------------------------------------------------------------------
// Finalize: reduce GRID_MAIN block partials with per-mode coefficients.
// bid < 2048 -> XY (negative coeff); else sym (x2 folds sum_{i!=j}).
// ---------------------------------------------------------------------------
__global__ __launch_bounds__(256) void mmd_final(
    const double* __restrict__ partials, float* __restrict__ out)
{
    const int tid = threadIdx.x;
    const double cs = 2.0 / (8192.0 * 8191.0);       // sym modes
    const double cx = -2.0 / (8192.0 * 8192.0);      // XY

    double s = 0.0;
    for (int idx = tid; idx < GRID_MAIN; idx += 256) {
        double c = (idx < 2048) ? cx : cs;
        s += partials[idx] * c;
    }
#pragma unroll
    for (int off = 32; off; off >>= 1) s += __shfl_xor(s, off, 64);

    __shared__ double wsum[4];
    const int lane = tid & 63, wid = tid >> 6;
    if (lane == 0) wsum[wid] = s;
    __syncthreads();
    if (tid == 0) {
        double mmd = wsum[0] + wsum[1] + wsum[2] + wsum[3];
        out[0] = (float)(mmd > 0.0 ? mmd : 0.0);
    }
}

// ---------------------------------------------------------------------------
extern "C" void kernel_launch(void* const* d_in, const int* in_sizes, int n_in,
                              void* d_out, int out_size, void* d_ws, size_t ws_size,
                              hipStream_t stream) {
    const float* z_seq   = (const float*)d_in[0];   // [16,512,64]
    const float* pmean   = (const float*)d_in[1];   // [64]
    const float* pstd    = (const float*)d_in[2];   // [64]
    const float* z_prior = (const float*)d_in[3];   // [8192,64]
    float* out = (float*)d_out;

    char* ws = (char*)d_ws;
    __hip_bfloat16* Xb = (__hip_bfloat16*)(ws);                    // 1 MB
    __hip_bfloat16* Yb = (__hip_bfloat16*)(ws + (1u << 20));       // 1 MB
    float* sxx = (float*)(ws + (2u << 20));                        // 32 KB
    float* syy = (float*)(ws + (2u << 20) + 32768);                // 32 KB
    double* partials = (double*)(ws + (2u << 20) + 65536);         // ~33 KB

    mmd_prep<<<dim3(1024), dim3(256), 0, stream>>>(
        z_seq, pmean, pstd, z_prior, Xb, Yb, sxx, syy);
    mmd_main<<<dim3(GRID_MAIN), dim3(256), 0, stream>>>(
        Xb, Yb, sxx, syy, partials);
    mmd_final<<<dim3(1), dim3(256), 0, stream>>>(partials, out);
}